// Round 9
// baseline (510.498 us; speedup 1.0000x reference)
//
#include <hip/hip_runtime.h>

typedef unsigned short u16;
typedef unsigned int u32;
typedef u16 u16x8 __attribute__((ext_vector_type(8)));
typedef u32 u32x2 __attribute__((ext_vector_type(2)));
typedef u32 u32x4 __attribute__((ext_vector_type(4)));
typedef __bf16 bf16x8 __attribute__((ext_vector_type(8)));
typedef float f32x4 __attribute__((ext_vector_type(4)));
typedef float f32x16 __attribute__((ext_vector_type(16)));

typedef __attribute__((address_space(1))) const u32 gas_u32;
typedef __attribute__((address_space(3))) u32 las_u32;

__device__ __forceinline__ u16 f2bf(float f) {
  unsigned u = __builtin_bit_cast(unsigned, f);
  u += 0x7FFF + ((u >> 16) & 1);   // RNE
  return (u16)(u >> 16);
}

__device__ __forceinline__ float fast_exp2(float x) {
  return __builtin_amdgcn_exp2f(x);
}

__device__ __forceinline__ f32x4 mfma16(u16x8 a, u16x8 b, f32x4 c) {
  return __builtin_amdgcn_mfma_f32_16x16x32_bf16(
      __builtin_bit_cast(bf16x8, a), __builtin_bit_cast(bf16x8, b), c, 0, 0, 0);
}

__device__ __forceinline__ f32x16 mfma32(u16x8 a, u16x8 b, f32x16 c) {
  return __builtin_amdgcn_mfma_f32_32x32x16_bf16(
      __builtin_bit_cast(bf16x8, a), __builtin_bit_cast(bf16x8, b), c, 0, 0, 0);
}

__device__ __forceinline__ u32 cvt_pk_bf16(float lo, float hi) {
  u32 r;
  asm("v_cvt_pk_bf16_f32 %0, %1, %2" : "=v"(r) : "v"(lo), "v"(hi));
  return r;
}

// async global->LDS, 16B per lane (linear LDS dest = wave-uniform base + lane*16)
__device__ __forceinline__ void gload_lds16(const u16* g, u16* l) {
  __builtin_amdgcn_global_load_lds((gas_u32*)(const void*)g, (las_u32*)(void*)l, 16, 0, 0);
}

// ---------------------------------------------------------------- constants
constexpr int DM   = 1024;   // d_model
constexpr int GK   = 1024;   // GEMM K
constexpr int SEQ  = 2048;
constexpr int NB   = 4;
constexpr int NH   = 16;

// ---------------------------------------------------------------- fused fp32 -> bf16 cast (q,k,v)
__global__ __launch_bounds__(256) void cast3_kernel(const float* __restrict__ q,
                                                    const float* __restrict__ k,
                                                    const float* __restrict__ v,
                                                    u16* __restrict__ out) {
  const int t = blockIdx.y;
  const float* in = t == 0 ? q : (t == 1 ? k : v);
  u16* dst = out + (size_t)t * 8192 * 1024;
  const int i = blockIdx.x * 256 + threadIdx.x;
  float4 a = ((const float4*)in)[2 * i];
  float4 b = ((const float4*)in)[2 * i + 1];
  u16x8 o = {f2bf(a.x), f2bf(a.y), f2bf(a.z), f2bf(a.w),
             f2bf(b.x), f2bf(b.y), f2bf(b.z), f2bf(b.w)};
  *(u16x8*)(dst + (size_t)i * 8) = o;
}

// ---------------------------------------------------------------- fused weight transpose+cast (4 W)
__global__ void transpose4_kernel(const float* __restrict__ Wq, const float* __restrict__ Wk,
                                  const float* __restrict__ Wv, const float* __restrict__ Wo,
                                  u16* __restrict__ Wt) {
  __shared__ float tile[32][33];
  const int z = blockIdx.z;
  const float* W = z == 0 ? Wq : (z == 1 ? Wk : (z == 2 ? Wv : Wo));
  u16* dst = Wt + (size_t)z * DM * DM;
  const int tx = threadIdx.x;          // 0..31
  const int ty = threadIdx.y;          // 0..7
  const int n0 = blockIdx.x * 32;
  const int k0 = blockIdx.y * 32;
#pragma unroll
  for (int i = 0; i < 4; ++i)
    tile[ty + i * 8][tx] = W[(size_t)(k0 + ty + i * 8) * DM + n0 + tx];
  __syncthreads();
#pragma unroll
  for (int i = 0; i < 4; ++i)
    dst[(size_t)(n0 + ty + i * 8) * DM + k0 + tx] = f2bf(tile[tx][ty + i * 8]);
}

// ---------------------------------------------------------------- valid_len from key padding mask
__global__ void vlen_kernel(const int* __restrict__ mask, int* __restrict__ vlen) {
  const int b = blockIdx.x;
  const int t = threadIdx.x;
  __shared__ int cnt[256];
  int c = 0;
  for (int s = t; s < SEQ; s += 256) c += (mask[b * SEQ + s] == 0) ? 1 : 0;
  cnt[t] = c;
  __syncthreads();
  for (int off = 128; off > 0; off >>= 1) {
    if (t < off) cnt[t] += cnt[t + off];
    __syncthreads();
  }
  if (t == 0) vlen[b] = cnt[0];
}

// ---------------------------------------------------------------- fused QKV GEMM (one dispatch)
// XCD-swizzled 1D grid (1536): each XCD owns an m-band (8 A-panels resident in its L2).
__global__ __launch_bounds__(256) void gemm_qkv_kernel(const u16* __restrict__ Aall,
                                                       const u16* __restrict__ Bt3,
                                                       const float* __restrict__ bq,
                                                       const float* __restrict__ bk,
                                                       const float* __restrict__ bv,
                                                       u16* __restrict__ Qm,
                                                       u16* __restrict__ Km,
                                                       u16* __restrict__ Vtm,
                                                       float qscale) {
  __shared__ __align__(16) u16 sA[128 * 64];
  __shared__ __align__(16) u16 sB[128 * 64];
  const int tid  = threadIdx.x;
  const int lane = tid & 63;
  const int w    = tid >> 6;
  const int wm   = (w >> 1) * 64;
  const int wn   = (w & 1) * 64;
  const int lrow = lane & 15;
  const int lk   = (lane >> 4) * 8;
  // XCD swizzle: XCD k = o&7 gets m-panels [8k,8k+8), n fast within
  const int o  = blockIdx.x;
  const int k  = o & 7, j = o >> 3;       // j 0..191
  const int n0 = (j >> 3) * 128;          // 0..2944
  const int m0 = (k * 8 + (j & 7)) * 128; // 0..8064
  const int sel = n0 >> 10;

  const u16* Ab = Aall + (size_t)sel * 8192 * 1024 + (size_t)m0 * GK;
  const u16* Bb = Bt3 + (size_t)n0 * GK;
  const float* bias = sel == 0 ? bq : (sel == 1 ? bk : bv);
  const float osc = sel == 0 ? qscale : 1.f;
  u16* outp = sel == 0 ? Qm : (sel == 1 ? Km : Vtm);

  f32x4 acc[4][4] = {};

  for (int kt = 0; kt < GK; kt += 64) {
    __syncthreads();
#pragma unroll
    for (int i = 0; i < 4; ++i) {
      const int seg = tid + i * 256;
      const int row = seg >> 3, c8 = (seg & 7) * 8;
      gload_lds16(Ab + (size_t)row * GK + kt + c8, &sA[row * 64 + c8]);
      gload_lds16(Bb + (size_t)row * GK + kt + c8, &sB[row * 64 + c8]);
    }
    __syncthreads();   // drains vmcnt
#pragma unroll
    for (int kk = 0; kk < 64; kk += 32) {
      u16x8 am[4], bn[4];
#pragma unroll
      for (int m = 0; m < 4; ++m)
        am[m] = *(const u16x8*)(&sA[(wm + m * 16 + lrow) * 64 + kk + lk]);
#pragma unroll
      for (int n = 0; n < 4; ++n)
        bn[n] = *(const u16x8*)(&sB[(wn + n * 16 + lrow) * 64 + kk + lk]);
#pragma unroll
      for (int m = 0; m < 4; ++m)
#pragma unroll
        for (int n = 0; n < 4; ++n)
          acc[m][n] = mfma16(am[m], bn[n], acc[m][n]);
    }
  }

  const int r0 = (lane >> 4) * 4;
#pragma unroll
  for (int m = 0; m < 4; ++m) {
#pragma unroll
    for (int n = 0; n < 4; ++n) {
      const int col = n0 + wn + n * 16 + lrow;
      const int c = col & 1023;
      const float bval = bias[c];
      const int h = c >> 6, d = c & 63;
#pragma unroll
      for (int r = 0; r < 4; ++r) {
        const int row = m0 + wm + m * 16 + r0 + r;
        const float v = (acc[m][n][r] + bval) * osc;
        const int bb = row >> 11, s = row & (SEQ - 1);
        size_t off;
        if (sel == 2) off = (((size_t)(bb * NH + h)) * 64 + d) * SEQ + s;
        else          off = (((size_t)(bb * NH + h)) * SEQ + s) * 64 + d;
        outp[off] = f2bf(v);
      }
    }
  }
}

// ---------------------------------------------------------------- output GEMM (fp32 out)
__global__ __launch_bounds__(256) void gemm_o_kernel(const u16* __restrict__ A,
                                                     const u16* __restrict__ Bt,
                                                     const float* __restrict__ bias,
                                                     float* __restrict__ out) {
  __shared__ __align__(16) u16 sA[128 * 64];
  __shared__ __align__(16) u16 sB[128 * 64];
  const int tid  = threadIdx.x;
  const int lane = tid & 63;
  const int w    = tid >> 6;
  const int wm   = (w >> 1) * 64;
  const int wn   = (w & 1) * 64;
  const int lrow = lane & 15;
  const int lk   = (lane >> 4) * 8;
  const int o  = blockIdx.x;              // 512 blocks
  const int k  = o & 7, j = o >> 3;       // j 0..63
  const int n0 = (j >> 3) * 128;
  const int m0 = (k * 8 + (j & 7)) * 128;

  const u16* Ab = A + (size_t)m0 * GK;
  const u16* Bb = Bt + (size_t)n0 * GK;

  f32x4 acc[4][4] = {};

  for (int kt = 0; kt < GK; kt += 64) {
    __syncthreads();
#pragma unroll
    for (int i = 0; i < 4; ++i) {
      const int seg = tid + i * 256;
      const int row = seg >> 3, c8 = (seg & 7) * 8;
      gload_lds16(Ab + (size_t)row * GK + kt + c8, &sA[row * 64 + c8]);
      gload_lds16(Bb + (size_t)row * GK + kt + c8, &sB[row * 64 + c8]);
    }
    __syncthreads();
#pragma unroll
    for (int kk = 0; kk < 64; kk += 32) {
      u16x8 am[4], bn[4];
#pragma unroll
      for (int m = 0; m < 4; ++m)
        am[m] = *(const u16x8*)(&sA[(wm + m * 16 + lrow) * 64 + kk + lk]);
#pragma unroll
      for (int n = 0; n < 4; ++n)
        bn[n] = *(const u16x8*)(&sB[(wn + n * 16 + lrow) * 64 + kk + lk]);
#pragma unroll
      for (int m = 0; m < 4; ++m)
#pragma unroll
        for (int n = 0; n < 4; ++n)
          acc[m][n] = mfma16(am[m], bn[n], acc[m][n]);
    }
  }

  const int r0 = (lane >> 4) * 4;
#pragma unroll
  for (int m = 0; m < 4; ++m) {
#pragma unroll
    for (int n = 0; n < 4; ++n) {
      const int col = n0 + wn + n * 16 + lrow;
      const float bval = bias[col];
#pragma unroll
      for (int r = 0; r < 4; ++r) {
        const int row = m0 + wm + m * 16 + r0 + r;
        out[(size_t)row * DM + col] = acc[m][n][r] + bval;
      }
    }
  }
}

// ---------------------------------------------------------------- flash attention (swapped-QK 32x32)
// Q (pre-scaled by 0.125*log2e), K: bf16 [B,H,S,64]; Vt: bf16 [B,H,64,S]; att: bf16 [B,S,H*64]
// 4 waves x 32 q = 128 q/block. KVBLK=64. Reg-staged T14 double-buffer (issue-early/write-late).
// XCD-swizzled 1D grid (1024): each XCD owns 8 bh (4 MB K/V working set = one L2).
__global__ __launch_bounds__(256, 5) void attn_kernel(const u16* __restrict__ Qm,
                                                      const u16* __restrict__ Km,
                                                      const u16* __restrict__ Vtm,
                                                      const int* __restrict__ vlen,
                                                      u16* __restrict__ att) {
  __shared__ __align__(16) u16 smem[16384];  // 32 KB: buf b at b*8192 (K 4096 elems, V 4096)
  const int tid  = threadIdx.x;
  const int lane = tid & 63;
  const int w    = tid >> 6;
  const int ql   = lane & 31;
  const int hi   = lane >> 5;
  const int hi4  = hi * 4;
  // XCD swizzle: XCD k gets bh in [8k,8k+8); heavy qb first within bh
  const int o  = blockIdx.x;
  const int t  = (o & 7) * 128 + (o >> 3);
  const int bh = t >> 4;
  const int qb = 15 - (t & 15);
  const int b    = bh >> 4;
  const int h    = bh & 15;
  const int valid = vlen[b];
  const int q0   = qb * 128;
  const int q0w  = q0 + w * 32;
  const int qg   = q0w + ql;
  const float NEGB = -1e30f;

  const u16* Qbase = Qm + ((size_t)bh * SEQ + qg) * 64 + hi * 8;
  u16x8 qf[4];
#pragma unroll
  for (int s = 0; s < 4; ++s) qf[s] = *(const u16x8*)(Qbase + s * 16);

  f32x16 acc_o[2] = {};
  float m_run = NEGB, l_run = 0.f;

  const int kb_max = min((q0 + 127) >> 6, (valid - 1) >> 6);
  const int rel_base = min(qg, valid - 1);

  const u16* Kg = Km + (size_t)bh * SEQ * 64;
  const u16* Vg = Vtm + (size_t)bh * 64 * SEQ;

  // per-thread tile fragment: 2x16B of K + 2x16B of V
  auto LOADREGS = [&](int kb, u16x8 r[4]) {
#pragma unroll
    for (int i = 0; i < 4; ++i) {
      const int s = (tid + i * 256) & 511;
      const int row = s >> 3, c = s & 7;
      if (i < 2) r[i] = *(const u16x8*)(Kg + (size_t)(kb * 64 + row) * 64 + c * 8);
      else       r[i] = *(const u16x8*)(Vg + (size_t)row * SEQ + kb * 64 + c * 8);
    }
  };
  auto WRITELDS = [&](int buf, u16x8 r[4]) {
#pragma unroll
    for (int i = 0; i < 4; ++i) {
      const int s = (tid + i * 256) & 511;
      const int row = s >> 3, c = s & 7;
      const int dst = buf * 8192 + (i < 2 ? 0 : 4096) + row * 64 + ((c ^ (row & 7)) * 8);
      *(u16x8*)(smem + dst) = r[i];
    }
  };

  {
    u16x8 st[4];
    LOADREGS(0, st);
    WRITELDS(0, st);
  }
  __syncthreads();
  int buf = 0;

  for (int kb = 0; kb <= kb_max; ++kb) {
    u16x8 nx[4];
    if (kb < kb_max) LOADREGS(kb + 1, nx);   // issue loads early (T14)

    if (kb * 64 <= q0w + 31) {   // wave has unmasked work in this tile
      const char* kptr = (const char*)(smem + buf * 8192);
      const char* vptr = kptr + 8192;

      // ---- QK^T: S^T[k][q] (log2 domain; Q pre-scaled)
      f32x16 s_acc[2] = {};
      __builtin_amdgcn_s_setprio(1);
#pragma unroll
      for (int ch = 0; ch < 2; ++ch) {
#pragma unroll
        for (int s = 0; s < 4; ++s) {
          const int krow = ch * 32 + ql;
          const int off = (krow * 128 + s * 32 + hi * 16) ^ ((krow & 7) << 4);
          u16x8 kf = *(const u16x8*)(kptr + off);
          s_acc[ch] = mfma32(kf, qf[s], s_acc[ch]);
        }
      }
      __builtin_amdgcn_s_setprio(0);

      // ---- mask (skipped on interior tiles) + row max
      const int rel = rel_base - kb * 64;
      const bool full = (kb * 64 + 63 <= q0w) && ((kb + 1) * 64 <= valid);
      float mrow = NEGB;
      if (full) {
#pragma unroll
        for (int ch = 0; ch < 2; ++ch)
#pragma unroll
          for (int r = 0; r < 16; ++r) mrow = fmaxf(mrow, s_acc[ch][r]);
      } else {
#pragma unroll
        for (int ch = 0; ch < 2; ++ch)
#pragma unroll
          for (int r = 0; r < 16; ++r) {
            const int koff = ch * 32 + (r & 3) + 8 * (r >> 2) + hi4;
            float tv = s_acc[ch][r];
            tv = (koff > rel) ? NEGB : tv;
            s_acc[ch][r] = tv;
            mrow = fmaxf(mrow, tv);
          }
      }
      mrow = fmaxf(mrow, __shfl_xor(mrow, 32));

      // ---- defer-max (T13)
      if (!__all(mrow - m_run <= 8.f)) {
        const float mnew = fmaxf(m_run, mrow);
        const float sc_o = fast_exp2(m_run - mnew);
        m_run = mnew;
        l_run *= sc_o;
#pragma unroll
        for (int dc = 0; dc < 2; ++dc)
#pragma unroll
          for (int r = 0; r < 16; ++r) acc_o[dc][r] *= sc_o;
      }
      float rs = 0.f;
#pragma unroll
      for (int ch = 0; ch < 2; ++ch)
#pragma unroll
        for (int r = 0; r < 16; ++r) {
          const float p = fast_exp2(s_acc[ch][r] - m_run);
          s_acc[ch][r] = p;
          rs += p;
        }
      rs += __shfl_xor(rs, 32);
      l_run += rs;

      // ---- P^T -> B-operand frags via cvt_pk + permlane32_swap
      u16x8 pa[4];
#pragma unroll
      for (int ch = 0; ch < 2; ++ch) {
#pragma unroll
        for (int half = 0; half < 2; ++half) {
          const int pb = half * 8;
          u32 x0 = cvt_pk_bf16(s_acc[ch][pb + 0], s_acc[ch][pb + 1]);
          u32 x1 = cvt_pk_bf16(s_acc[ch][pb + 2], s_acc[ch][pb + 3]);
          u32 y0 = cvt_pk_bf16(s_acc[ch][pb + 4], s_acc[ch][pb + 5]);
          u32 y1 = cvt_pk_bf16(s_acc[ch][pb + 6], s_acc[ch][pb + 7]);
          u32x2 r0 = __builtin_amdgcn_permlane32_swap(x0, y0, false, false);
          u32x2 r1 = __builtin_amdgcn_permlane32_swap(x1, y1, false, false);
          u32x4 wds = {r0[0], r1[0], r0[1], r1[1]};
          pa[ch * 2 + half] = __builtin_bit_cast(u16x8, wds);
        }
      }

      // ---- PV: O^T[d][q] += V^T[d][k] * P^T[k][q]
      __builtin_amdgcn_s_setprio(1);
#pragma unroll
      for (int dc = 0; dc < 2; ++dc) {
#pragma unroll
        for (int ks = 0; ks < 4; ++ks) {
          const int drow = dc * 32 + ql;
          const int off = (drow * 128 + ks * 32 + hi * 16) ^ ((drow & 7) << 4);
          u16x8 vf = *(const u16x8*)(vptr + off);
          acc_o[dc] = mfma32(vf, pa[ks], acc_o[dc]);
        }
      }
      __builtin_amdgcn_s_setprio(0);
    }

    if (kb < kb_max) WRITELDS(buf ^ 1, nx);  // write-late: other buffer, post-compute
    __syncthreads();
    buf ^= 1;
  }

  // ---- epilogue: normalize, transpose via LDS, coalesced store
  const float inv_l = 1.f / l_run;
  char* wbase = (char*)smem + w * 4096;   // per-wave 32q x 64d bf16 region
#pragma unroll
  for (int dc = 0; dc < 2; ++dc)
#pragma unroll
    for (int rg = 0; rg < 4; ++rg) {
      u32 lo  = cvt_pk_bf16(acc_o[dc][rg * 4 + 0] * inv_l, acc_o[dc][rg * 4 + 1] * inv_l);
      u32 hiw = cvt_pk_bf16(acc_o[dc][rg * 4 + 2] * inv_l, acc_o[dc][rg * 4 + 3] * inv_l);
      const int dbase = dc * 32 + rg * 8 + hi4;
      const int off = (ql * 128 + dbase * 2) ^ ((ql & 7) << 4);
      u32x2 pr = {lo, hiw};
      *(u32x2*)(wbase + off) = pr;
    }
  __syncthreads();
  u16* attb = att + ((size_t)b * SEQ + q0) * DM + h * 64;
#pragma unroll
  for (int i = 0; i < 4; ++i) {
    const int seg = tid + i * 256;       // 1024 segs of 16B
    const int qr = seg >> 3, c = seg & 7;
    const int off = ((qr & 31) * 128 + c * 16) ^ ((qr & 7) << 4);
    u16x8 vvv = *(const u16x8*)((char*)smem + (qr >> 5) * 4096 + off);
    *(u16x8*)(attb + (size_t)qr * DM + c * 8) = vvv;
  }
}

// ---------------------------------------------------------------- launch
extern "C" void kernel_launch(void* const* d_in, const int* in_sizes, int n_in,
                              void* d_out, int out_size, void* d_ws, size_t ws_size,
                              hipStream_t stream) {
  const float* q_in = (const float*)d_in[0];
  const float* k_in = (const float*)d_in[1];
  const float* v_in = (const float*)d_in[2];
  const int*   kpm  = (const int*)d_in[3];
  const float* Wq   = (const float*)d_in[4];
  const float* bq   = (const float*)d_in[5];
  const float* Wk   = (const float*)d_in[6];
  const float* bk   = (const float*)d_in[7];
  const float* Wv   = (const float*)d_in[8];
  const float* bv   = (const float*)d_in[9];
  const float* Wo   = (const float*)d_in[10];
  const float* bo   = (const float*)d_in[11];

  char* ws = (char*)d_ws;
  const size_t WSZ = (size_t)1 << 21;   // 2 MB per transposed weight
  const size_t TSZ = (size_t)1 << 24;   // 16 MB per bf16 [8192,1024] tensor
  u16* wqkv_t = (u16*)(ws);                          // [3072][1024] (+ Wo at 3*WSZ)
  u16* wo_t   = (u16*)(ws + 3 * WSZ);
  u16* qkvA   = (u16*)(ws + 4 * WSZ);                // 3 contiguous bf16 activations
  u16* Qm     = (u16*)(ws + 4 * WSZ + 3 * TSZ);
  u16* Km     = (u16*)(ws + 4 * WSZ + 4 * TSZ);
  u16* Vtm    = (u16*)(ws + 4 * WSZ + 5 * TSZ);
  u16* attb   = qkvA;                                // alias: qkvA dead after QKV-GEMM
  int* vlen   = (int*)(ws + 4 * WSZ + 6 * TSZ);

  const float SC = 0.18033688011112042f;  // 0.125 * log2(e), folded into Q

  vlen_kernel<<<NB, 256, 0, stream>>>(kpm, vlen);
  transpose4_kernel<<<dim3(32, 32, 4), dim3(32, 8), 0, stream>>>(Wq, Wk, Wv, Wo, wqkv_t);
  cast3_kernel<<<dim3(4096, 3), 256, 0, stream>>>(q_in, k_in, v_in, qkvA);

  gemm_qkv_kernel<<<1536, 256, 0, stream>>>(qkvA, wqkv_t, bq, bk, bv, Qm, Km, Vtm, SC);

  attn_kernel<<<1024, 256, 0, stream>>>(Qm, Km, Vtm, vlen, attb);

  gemm_o_kernel<<<512, 256, 0, stream>>>(attb, wo_t, bo, (float*)d_out);
}

// Round 10
// 354.339 us; speedup vs baseline: 1.4407x; 1.4407x over previous
//
#include <hip/hip_runtime.h>

typedef unsigned short u16;
typedef unsigned int u32;
typedef u16 u16x8 __attribute__((ext_vector_type(8)));
typedef u32 u32x2 __attribute__((ext_vector_type(2)));
typedef u32 u32x4 __attribute__((ext_vector_type(4)));
typedef __bf16 bf16x8 __attribute__((ext_vector_type(8)));
typedef float f32x4 __attribute__((ext_vector_type(4)));
typedef float f32x16 __attribute__((ext_vector_type(16)));

typedef __attribute__((address_space(1))) const u32 gas_u32;
typedef __attribute__((address_space(3))) u32 las_u32;

__device__ __forceinline__ u16 f2bf(float f) {
  unsigned u = __builtin_bit_cast(unsigned, f);
  u += 0x7FFF + ((u >> 16) & 1);   // RNE
  return (u16)(u >> 16);
}

__device__ __forceinline__ float fast_exp2(float x) {
  return __builtin_amdgcn_exp2f(x);
}

__device__ __forceinline__ f32x4 mfma16(u16x8 a, u16x8 b, f32x4 c) {
  return __builtin_amdgcn_mfma_f32_16x16x32_bf16(
      __builtin_bit_cast(bf16x8, a), __builtin_bit_cast(bf16x8, b), c, 0, 0, 0);
}

__device__ __forceinline__ f32x16 mfma32(u16x8 a, u16x8 b, f32x16 c) {
  return __builtin_amdgcn_mfma_f32_32x32x16_bf16(
      __builtin_bit_cast(bf16x8, a), __builtin_bit_cast(bf16x8, b), c, 0, 0, 0);
}

__device__ __forceinline__ u32 cvt_pk_bf16(float lo, float hi) {
  u32 r;
  asm("v_cvt_pk_bf16_f32 %0, %1, %2" : "=v"(r) : "v"(lo), "v"(hi));
  return r;
}

// async global->LDS, 16B per lane (linear LDS dest = wave-uniform base + lane*16)
__device__ __forceinline__ void gload_lds16(const u16* g, u16* l) {
  __builtin_amdgcn_global_load_lds((gas_u32*)(const void*)g, (las_u32*)(void*)l, 16, 0, 0);
}

// ---------------------------------------------------------------- constants
constexpr int DM   = 1024;   // d_model
constexpr int GK   = 1024;   // GEMM K
constexpr int SEQ  = 2048;
constexpr int NB   = 4;
constexpr int NH   = 16;

// ---------------------------------------------------------------- fused fp32 -> bf16 cast (q,k,v)
__global__ __launch_bounds__(256) void cast3_kernel(const float* __restrict__ q,
                                                    const float* __restrict__ k,
                                                    const float* __restrict__ v,
                                                    u16* __restrict__ out) {
  const int t = blockIdx.y;
  const float* in = t == 0 ? q : (t == 1 ? k : v);
  u16* dst = out + (size_t)t * 8192 * 1024;
  const int i = blockIdx.x * 256 + threadIdx.x;
  float4 a = ((const float4*)in)[2 * i];
  float4 b = ((const float4*)in)[2 * i + 1];
  u16x8 o = {f2bf(a.x), f2bf(a.y), f2bf(a.z), f2bf(a.w),
             f2bf(b.x), f2bf(b.y), f2bf(b.z), f2bf(b.w)};
  *(u16x8*)(dst + (size_t)i * 8) = o;
}

// ---------------------------------------------------------------- fused weight transpose+cast (4 W)
__global__ void transpose4_kernel(const float* __restrict__ Wq, const float* __restrict__ Wk,
                                  const float* __restrict__ Wv, const float* __restrict__ Wo,
                                  u16* __restrict__ Wt) {
  __shared__ float tile[32][33];
  const int z = blockIdx.z;
  const float* W = z == 0 ? Wq : (z == 1 ? Wk : (z == 2 ? Wv : Wo));
  u16* dst = Wt + (size_t)z * DM * DM;
  const int tx = threadIdx.x;          // 0..31
  const int ty = threadIdx.y;          // 0..7
  const int n0 = blockIdx.x * 32;
  const int k0 = blockIdx.y * 32;
#pragma unroll
  for (int i = 0; i < 4; ++i)
    tile[ty + i * 8][tx] = W[(size_t)(k0 + ty + i * 8) * DM + n0 + tx];
  __syncthreads();
#pragma unroll
  for (int i = 0; i < 4; ++i)
    dst[(size_t)(n0 + ty + i * 8) * DM + k0 + tx] = f2bf(tile[tx][ty + i * 8]);
}

// ---------------------------------------------------------------- valid_len from key padding mask
__global__ void vlen_kernel(const int* __restrict__ mask, int* __restrict__ vlen) {
  const int b = blockIdx.x;
  const int t = threadIdx.x;
  __shared__ int cnt[256];
  int c = 0;
  for (int s = t; s < SEQ; s += 256) c += (mask[b * SEQ + s] == 0) ? 1 : 0;
  cnt[t] = c;
  __syncthreads();
  for (int off = 128; off > 0; off >>= 1) {
    if (t < off) cnt[t] += cnt[t + off];
    __syncthreads();
  }
  if (t == 0) vlen[b] = cnt[0];
}

// ---------------------------------------------------------------- fused QKV GEMM (one dispatch)
// XCD-swizzled 1D grid (1536): each XCD owns an m-band (8 A-panels resident in its L2).
__global__ __launch_bounds__(256) void gemm_qkv_kernel(const u16* __restrict__ Aall,
                                                       const u16* __restrict__ Bt3,
                                                       const float* __restrict__ bq,
                                                       const float* __restrict__ bk,
                                                       const float* __restrict__ bv,
                                                       u16* __restrict__ Qm,
                                                       u16* __restrict__ Km,
                                                       u16* __restrict__ Vtm,
                                                       float qscale) {
  __shared__ __align__(16) u16 sA[128 * 64];
  __shared__ __align__(16) u16 sB[128 * 64];
  const int tid  = threadIdx.x;
  const int lane = tid & 63;
  const int w    = tid >> 6;
  const int wm   = (w >> 1) * 64;
  const int wn   = (w & 1) * 64;
  const int lrow = lane & 15;
  const int lk   = (lane >> 4) * 8;
  // XCD swizzle: XCD k = o&7 gets m-panels [8k,8k+8), n fast within
  const int o  = blockIdx.x;
  const int k  = o & 7, j = o >> 3;       // j 0..191
  const int n0 = (j >> 3) * 128;          // 0..2944
  const int m0 = (k * 8 + (j & 7)) * 128; // 0..8064
  const int sel = n0 >> 10;

  const u16* Ab = Aall + (size_t)sel * 8192 * 1024 + (size_t)m0 * GK;
  const u16* Bb = Bt3 + (size_t)n0 * GK;
  const float* bias = sel == 0 ? bq : (sel == 1 ? bk : bv);
  const float osc = sel == 0 ? qscale : 1.f;
  u16* outp = sel == 0 ? Qm : (sel == 1 ? Km : Vtm);

  f32x4 acc[4][4] = {};

  for (int kt = 0; kt < GK; kt += 64) {
    __syncthreads();
#pragma unroll
    for (int i = 0; i < 4; ++i) {
      const int seg = tid + i * 256;
      const int row = seg >> 3, c8 = (seg & 7) * 8;
      gload_lds16(Ab + (size_t)row * GK + kt + c8, &sA[row * 64 + c8]);
      gload_lds16(Bb + (size_t)row * GK + kt + c8, &sB[row * 64 + c8]);
    }
    __syncthreads();   // drains vmcnt
#pragma unroll
    for (int kk = 0; kk < 64; kk += 32) {
      u16x8 am[4], bn[4];
#pragma unroll
      for (int m = 0; m < 4; ++m)
        am[m] = *(const u16x8*)(&sA[(wm + m * 16 + lrow) * 64 + kk + lk]);
#pragma unroll
      for (int n = 0; n < 4; ++n)
        bn[n] = *(const u16x8*)(&sB[(wn + n * 16 + lrow) * 64 + kk + lk]);
#pragma unroll
      for (int m = 0; m < 4; ++m)
#pragma unroll
        for (int n = 0; n < 4; ++n)
          acc[m][n] = mfma16(am[m], bn[n], acc[m][n]);
    }
  }

  const int r0 = (lane >> 4) * 4;
#pragma unroll
  for (int m = 0; m < 4; ++m) {
#pragma unroll
    for (int n = 0; n < 4; ++n) {
      const int col = n0 + wn + n * 16 + lrow;
      const int c = col & 1023;
      const float bval = bias[c];
      const int h = c >> 6, d = c & 63;
#pragma unroll
      for (int r = 0; r < 4; ++r) {
        const int row = m0 + wm + m * 16 + r0 + r;
        const float v = (acc[m][n][r] + bval) * osc;
        const int bb = row >> 11, s = row & (SEQ - 1);
        size_t off;
        if (sel == 2) off = (((size_t)(bb * NH + h)) * 64 + d) * SEQ + s;
        else          off = (((size_t)(bb * NH + h)) * SEQ + s) * 64 + d;
        outp[off] = f2bf(v);
      }
    }
  }
}

// ---------------------------------------------------------------- output GEMM (fp32 out)
__global__ __launch_bounds__(256) void gemm_o_kernel(const u16* __restrict__ A,
                                                     const u16* __restrict__ Bt,
                                                     const float* __restrict__ bias,
                                                     float* __restrict__ out) {
  __shared__ __align__(16) u16 sA[128 * 64];
  __shared__ __align__(16) u16 sB[128 * 64];
  const int tid  = threadIdx.x;
  const int lane = tid & 63;
  const int w    = tid >> 6;
  const int wm   = (w >> 1) * 64;
  const int wn   = (w & 1) * 64;
  const int lrow = lane & 15;
  const int lk   = (lane >> 4) * 8;
  const int o  = blockIdx.x;              // 512 blocks
  const int k  = o & 7, j = o >> 3;       // j 0..63
  const int n0 = (j >> 3) * 128;
  const int m0 = (k * 8 + (j & 7)) * 128;

  const u16* Ab = A + (size_t)m0 * GK;
  const u16* Bb = Bt + (size_t)n0 * GK;

  f32x4 acc[4][4] = {};

  for (int kt = 0; kt < GK; kt += 64) {
    __syncthreads();
#pragma unroll
    for (int i = 0; i < 4; ++i) {
      const int seg = tid + i * 256;
      const int row = seg >> 3, c8 = (seg & 7) * 8;
      gload_lds16(Ab + (size_t)row * GK + kt + c8, &sA[row * 64 + c8]);
      gload_lds16(Bb + (size_t)row * GK + kt + c8, &sB[row * 64 + c8]);
    }
    __syncthreads();
#pragma unroll
    for (int kk = 0; kk < 64; kk += 32) {
      u16x8 am[4], bn[4];
#pragma unroll
      for (int m = 0; m < 4; ++m)
        am[m] = *(const u16x8*)(&sA[(wm + m * 16 + lrow) * 64 + kk + lk]);
#pragma unroll
      for (int n = 0; n < 4; ++n)
        bn[n] = *(const u16x8*)(&sB[(wn + n * 16 + lrow) * 64 + kk + lk]);
#pragma unroll
      for (int m = 0; m < 4; ++m)
#pragma unroll
        for (int n = 0; n < 4; ++n)
          acc[m][n] = mfma16(am[m], bn[n], acc[m][n]);
    }
  }

  const int r0 = (lane >> 4) * 4;
#pragma unroll
  for (int m = 0; m < 4; ++m) {
#pragma unroll
    for (int n = 0; n < 4; ++n) {
      const int col = n0 + wn + n * 16 + lrow;
      const float bval = bias[col];
#pragma unroll
      for (int r = 0; r < 4; ++r) {
        const int row = m0 + wm + m * 16 + r0 + r;
        out[(size_t)row * DM + col] = acc[m][n][r] + bval;
      }
    }
  }
}

// ---------------------------------------------------------------- flash attention (swapped-QK 32x32)
// Q (pre-scaled by 0.125*log2e), K: bf16 [B,H,S,64]; Vt: bf16 [B,H,64,S]; att: bf16 [B,S,H*64]
// R6-proven body. LPT pairing: block does qb=p AND qb=15-p (uniform 34 tiles/block).
// XCD-swizzled grid (512): each XCD owns 8 bh (4 MB K/V = one L2).
__global__ __launch_bounds__(256) void attn_kernel(const u16* __restrict__ Qm,
                                                   const u16* __restrict__ Km,
                                                   const u16* __restrict__ Vtm,
                                                   const int* __restrict__ vlen,
                                                   u16* __restrict__ att) {
  __shared__ __align__(16) u16 smem[8192];            // 16 KB
  char* lds_k = (char*)smem;                          // K tile  [64 k][64 dh], swizzled
  char* lds_v = (char*)smem + 8192;                   // Vt tile [64 d][64 k],  swizzled
  const int tid  = threadIdx.x;
  const int lane = tid & 63;
  const int w    = tid >> 6;
  const int ql   = lane & 31;
  const int hi   = lane >> 5;
  const int hi4  = hi * 4;
  // XCD swizzle + pairing: o -> (bh, pidx)
  const int o   = blockIdx.x;                 // 0..511
  const int t   = (o & 7) * 64 + (o >> 3);    // bijective
  const int bh  = t >> 3;
  const int pidx = t & 7;
  const int b    = bh >> 4;
  const int h    = bh & 15;
  const int valid = vlen[b];
  const float NEGB = -1e30f;

  const u16* Kg = Km + (size_t)bh * SEQ * 64;
  const u16* Vg = Vtm + (size_t)bh * 64 * SEQ;

  for (int pass = 0; pass < 2; ++pass) {
    const int qb  = pass == 0 ? pidx : 15 - pidx;
    const int q0  = qb * 128;
    const int q0w = q0 + w * 32;
    const int qg  = q0w + ql;

    const u16* Qbase = Qm + ((size_t)bh * SEQ + qg) * 64 + hi * 8;
    u16x8 qf[4];
#pragma unroll
    for (int s = 0; s < 4; ++s) qf[s] = *(const u16x8*)(Qbase + s * 16);

    f32x16 acc_o[2] = {};
    float m_run = NEGB, l_run = 0.f;

    const int kb_max = min((q0 + 127) >> 6, (valid - 1) >> 6);
    const int rel_base = min(qg, valid - 1);

    for (int kb = 0; kb <= kb_max; ++kb) {
      __syncthreads();
      // stage K and V^T tiles (reg -> swizzled ds_write: byte ^= (row&7)<<4)
#pragma unroll
      for (int i = 0; i < 2; ++i) {
        const int seg = tid + i * 256;   // 512 segs of 16B per tile
        const int row = seg >> 3, c = seg & 7;
        const int dst = (row * 128 + c * 16) ^ ((row & 7) << 4);
        *(u16x8*)(lds_k + dst) = *(const u16x8*)(Kg + ((size_t)(kb * 64 + row)) * 64 + c * 8);
        *(u16x8*)(lds_v + dst) = *(const u16x8*)(Vg + (size_t)row * SEQ + kb * 64 + c * 8);
      }
      __syncthreads();

      if (kb * 64 > q0w + 31) continue;  // tile fully masked for this wave

      // ---- QK^T: S^T[k][q] (log2 domain; Q pre-scaled)
      f32x16 s_acc[2] = {};
      __builtin_amdgcn_s_setprio(1);
#pragma unroll
      for (int ch = 0; ch < 2; ++ch) {
#pragma unroll
        for (int s = 0; s < 4; ++s) {
          const int krow = ch * 32 + ql;
          const int off = (krow * 128 + s * 32 + hi * 16) ^ ((krow & 7) << 4);
          u16x8 kf = *(const u16x8*)(lds_k + off);
          s_acc[ch] = mfma32(kf, qf[s], s_acc[ch]);
        }
      }
      __builtin_amdgcn_s_setprio(0);

      // ---- mask + online softmax (lane-local per q)
      const int rel = rel_base - kb * 64;
      float mrow = NEGB;
#pragma unroll
      for (int ch = 0; ch < 2; ++ch)
#pragma unroll
        for (int r = 0; r < 16; ++r) {
          const int koff = ch * 32 + (r & 3) + 8 * (r >> 2) + hi4;
          float tv = s_acc[ch][r];
          tv = (koff > rel) ? NEGB : tv;
          s_acc[ch][r] = tv;
          mrow = fmaxf(mrow, tv);
        }
      mrow = fmaxf(mrow, __shfl_xor(mrow, 32));
      const float mnew = fmaxf(m_run, mrow);
      const float sc_o = fast_exp2(m_run - mnew);
      m_run = mnew;
      float rs = 0.f;
#pragma unroll
      for (int ch = 0; ch < 2; ++ch)
#pragma unroll
        for (int r = 0; r < 16; ++r) {
          const float p = fast_exp2(s_acc[ch][r] - mnew);
          s_acc[ch][r] = p;
          rs += p;
        }
      rs += __shfl_xor(rs, 32);
      l_run = l_run * sc_o + rs;
#pragma unroll
      for (int dc = 0; dc < 2; ++dc)
#pragma unroll
        for (int r = 0; r < 16; ++r) acc_o[dc][r] *= sc_o;

      // ---- P^T -> B-operand frags via cvt_pk + permlane32_swap
      u16x8 pa[4];
#pragma unroll
      for (int ch = 0; ch < 2; ++ch) {
#pragma unroll
        for (int half = 0; half < 2; ++half) {
          const int pb = half * 8;
          u32 x0 = cvt_pk_bf16(s_acc[ch][pb + 0], s_acc[ch][pb + 1]);
          u32 x1 = cvt_pk_bf16(s_acc[ch][pb + 2], s_acc[ch][pb + 3]);
          u32 y0 = cvt_pk_bf16(s_acc[ch][pb + 4], s_acc[ch][pb + 5]);
          u32 y1 = cvt_pk_bf16(s_acc[ch][pb + 6], s_acc[ch][pb + 7]);
          u32x2 r0 = __builtin_amdgcn_permlane32_swap(x0, y0, false, false);
          u32x2 r1 = __builtin_amdgcn_permlane32_swap(x1, y1, false, false);
          u32x4 wds = {r0[0], r1[0], r0[1], r1[1]};
          pa[ch * 2 + half] = __builtin_bit_cast(u16x8, wds);
        }
      }

      // ---- PV: O^T[d][q] += V^T[d][k] * P^T[k][q]
      __builtin_amdgcn_s_setprio(1);
#pragma unroll
      for (int dc = 0; dc < 2; ++dc) {
#pragma unroll
        for (int ks = 0; ks < 4; ++ks) {
          const int drow = dc * 32 + ql;
          const int off = (drow * 128 + ks * 32 + hi * 16) ^ ((drow & 7) << 4);
          u16x8 vf = *(const u16x8*)(lds_v + off);
          acc_o[dc] = mfma32(vf, pa[ks], acc_o[dc]);
        }
      }
      __builtin_amdgcn_s_setprio(0);
    }

    // ---- epilogue: normalize, transpose via LDS, coalesced store
    __syncthreads();
    const float inv_l = 1.f / l_run;
    char* wbase = (char*)smem + w * 4096;   // per-wave 32q x 64d bf16 region
#pragma unroll
    for (int dc = 0; dc < 2; ++dc)
#pragma unroll
      for (int rg = 0; rg < 4; ++rg) {
        u32 lo  = cvt_pk_bf16(acc_o[dc][rg * 4 + 0] * inv_l, acc_o[dc][rg * 4 + 1] * inv_l);
        u32 hiw = cvt_pk_bf16(acc_o[dc][rg * 4 + 2] * inv_l, acc_o[dc][rg * 4 + 3] * inv_l);
        const int dbase = dc * 32 + rg * 8 + hi4;
        const int off = (ql * 128 + dbase * 2) ^ ((ql & 7) << 4);
        u32x2 pr = {lo, hiw};
        *(u32x2*)(wbase + off) = pr;
      }
    __syncthreads();
    u16* attb = att + ((size_t)b * SEQ + q0) * DM + h * 64;
#pragma unroll
    for (int i = 0; i < 4; ++i) {
      const int seg = tid + i * 256;       // 1024 segs of 16B
      const int qr = seg >> 3, c = seg & 7;
      const int off = ((qr & 31) * 128 + c * 16) ^ ((qr & 7) << 4);
      u16x8 vvv = *(const u16x8*)((char*)smem + (qr >> 5) * 4096 + off);
      *(u16x8*)(attb + (size_t)qr * DM + c * 8) = vvv;
    }
  }
}

// ---------------------------------------------------------------- launch
extern "C" void kernel_launch(void* const* d_in, const int* in_sizes, int n_in,
                              void* d_out, int out_size, void* d_ws, size_t ws_size,
                              hipStream_t stream) {
  const float* q_in = (const float*)d_in[0];
  const float* k_in = (const float*)d_in[1];
  const float* v_in = (const float*)d_in[2];
  const int*   kpm  = (const int*)d_in[3];
  const float* Wq   = (const float*)d_in[4];
  const float* bq   = (const float*)d_in[5];
  const float* Wk   = (const float*)d_in[6];
  const float* bk   = (const float*)d_in[7];
  const float* Wv   = (const float*)d_in[8];
  const float* bv   = (const float*)d_in[9];
  const float* Wo   = (const float*)d_in[10];
  const float* bo   = (const float*)d_in[11];

  char* ws = (char*)d_ws;
  const size_t WSZ = (size_t)1 << 21;   // 2 MB per transposed weight
  const size_t TSZ = (size_t)1 << 24;   // 16 MB per bf16 [8192,1024] tensor
  u16* wqkv_t = (u16*)(ws);                          // [3072][1024] (+ Wo at 3*WSZ)
  u16* wo_t   = (u16*)(ws + 3 * WSZ);
  u16* qkvA   = (u16*)(ws + 4 * WSZ);                // 3 contiguous bf16 activations
  u16* Qm     = (u16*)(ws + 4 * WSZ + 3 * TSZ);
  u16* Km     = (u16*)(ws + 4 * WSZ + 4 * TSZ);
  u16* Vtm    = (u16*)(ws + 4 * WSZ + 5 * TSZ);
  u16* attb   = qkvA;                                // alias: qkvA dead after QKV-GEMM
  int* vlen   = (int*)(ws + 4 * WSZ + 6 * TSZ);

  const float SC = 0.18033688011112042f;  // 0.125 * log2(e), folded into Q

  vlen_kernel<<<NB, 256, 0, stream>>>(kpm, vlen);
  transpose4_kernel<<<dim3(32, 32, 4), dim3(32, 8), 0, stream>>>(Wq, Wk, Wv, Wo, wqkv_t);
  cast3_kernel<<<dim3(4096, 3), 256, 0, stream>>>(q_in, k_in, v_in, qkvA);

  gemm_qkv_kernel<<<1536, 256, 0, stream>>>(qkvA, wqkv_t, bq, bk, bv, Qm, Km, Vtm, SC);

  attn_kernel<<<512, 256, 0, stream>>>(Qm, Km, Vtm, vlen, attb);

  gemm_o_kernel<<<512, 256, 0, stream>>>(attb, wo_t, bo, (float*)d_out);
}

// Round 11
// 336.629 us; speedup vs baseline: 1.5165x; 1.0526x over previous
//
#include <hip/hip_runtime.h>

typedef unsigned short u16;
typedef unsigned int u32;
typedef u16 u16x8 __attribute__((ext_vector_type(8)));
typedef u32 u32x2 __attribute__((ext_vector_type(2)));
typedef u32 u32x4 __attribute__((ext_vector_type(4)));
typedef __bf16 bf16x8 __attribute__((ext_vector_type(8)));
typedef float f32x4 __attribute__((ext_vector_type(4)));
typedef float f32x16 __attribute__((ext_vector_type(16)));

typedef __attribute__((address_space(1))) const u32 gas_u32;
typedef __attribute__((address_space(3))) u32 las_u32;

__device__ __forceinline__ u16 f2bf(float f) {
  unsigned u = __builtin_bit_cast(unsigned, f);
  u += 0x7FFF + ((u >> 16) & 1);   // RNE
  return (u16)(u >> 16);
}

__device__ __forceinline__ float fast_exp2(float x) {
  return __builtin_amdgcn_exp2f(x);
}

__device__ __forceinline__ f32x4 mfma16(u16x8 a, u16x8 b, f32x4 c) {
  return __builtin_amdgcn_mfma_f32_16x16x32_bf16(
      __builtin_bit_cast(bf16x8, a), __builtin_bit_cast(bf16x8, b), c, 0, 0, 0);
}

__device__ __forceinline__ f32x16 mfma32(u16x8 a, u16x8 b, f32x16 c) {
  return __builtin_amdgcn_mfma_f32_32x32x16_bf16(
      __builtin_bit_cast(bf16x8, a), __builtin_bit_cast(bf16x8, b), c, 0, 0, 0);
}

__device__ __forceinline__ u32 cvt_pk_bf16(float lo, float hi) {
  u32 r;
  asm("v_cvt_pk_bf16_f32 %0, %1, %2" : "=v"(r) : "v"(lo), "v"(hi));
  return r;
}

// async global->LDS, 16B per lane (linear LDS dest = wave-uniform base + lane*16)
__device__ __forceinline__ void gload_lds16(const u16* g, u16* l) {
  __builtin_amdgcn_global_load_lds((gas_u32*)(const void*)g, (las_u32*)(void*)l, 16, 0, 0);
}

// ---------------------------------------------------------------- constants
constexpr int DM   = 1024;   // d_model
constexpr int GK   = 1024;   // GEMM K
constexpr int SEQ  = 2048;
constexpr int NB   = 4;
constexpr int NH   = 16;

// ---------------------------------------------------------------- fused fp32 -> bf16 cast (q,k,v)
__global__ __launch_bounds__(256) void cast3_kernel(const float* __restrict__ q,
                                                    const float* __restrict__ k,
                                                    const float* __restrict__ v,
                                                    u16* __restrict__ out) {
  const int t = blockIdx.y;
  const float* in = t == 0 ? q : (t == 1 ? k : v);
  u16* dst = out + (size_t)t * 8192 * 1024;
  const int i = blockIdx.x * 256 + threadIdx.x;
  float4 a = ((const float4*)in)[2 * i];
  float4 b = ((const float4*)in)[2 * i + 1];
  u16x8 o = {f2bf(a.x), f2bf(a.y), f2bf(a.z), f2bf(a.w),
             f2bf(b.x), f2bf(b.y), f2bf(b.z), f2bf(b.w)};
  *(u16x8*)(dst + (size_t)i * 8) = o;
}

// ---------------------------------------------------------------- fused weight transpose+cast (4 W)
__global__ void transpose4_kernel(const float* __restrict__ Wq, const float* __restrict__ Wk,
                                  const float* __restrict__ Wv, const float* __restrict__ Wo,
                                  u16* __restrict__ Wt) {
  __shared__ float tile[32][33];
  const int z = blockIdx.z;
  const float* W = z == 0 ? Wq : (z == 1 ? Wk : (z == 2 ? Wv : Wo));
  u16* dst = Wt + (size_t)z * DM * DM;
  const int tx = threadIdx.x;          // 0..31
  const int ty = threadIdx.y;          // 0..7
  const int n0 = blockIdx.x * 32;
  const int k0 = blockIdx.y * 32;
#pragma unroll
  for (int i = 0; i < 4; ++i)
    tile[ty + i * 8][tx] = W[(size_t)(k0 + ty + i * 8) * DM + n0 + tx];
  __syncthreads();
#pragma unroll
  for (int i = 0; i < 4; ++i)
    dst[(size_t)(n0 + ty + i * 8) * DM + k0 + tx] = f2bf(tile[tx][ty + i * 8]);
}

// ---------------------------------------------------------------- valid_len from key padding mask
__global__ void vlen_kernel(const int* __restrict__ mask, int* __restrict__ vlen) {
  const int b = blockIdx.x;
  const int t = threadIdx.x;
  __shared__ int cnt[256];
  int c = 0;
  for (int s = t; s < SEQ; s += 256) c += (mask[b * SEQ + s] == 0) ? 1 : 0;
  cnt[t] = c;
  __syncthreads();
  for (int off = 128; off > 0; off >>= 1) {
    if (t < off) cnt[t] += cnt[t + off];
    __syncthreads();
  }
  if (t == 0) vlen[b] = cnt[0];
}

// LDS tile addressing (T2 swizzle, rule #21 both-sides):
//   staging: LDS dest linear (slot = seg*16B); global source col = (c ^ (row&7))
//   read:    byte off = row*128 + ((c16 ^ (row&7)) << 4)
__device__ __forceinline__ u16x8 rd_swz(const u16* s, int row, int c16) {
  return *(const u16x8*)((const char*)s + row * 128 + (((c16 ^ (row & 7)) & 7) << 4));
}

// ---------------------------------------------------------------- fused QKV GEMM (one dispatch)
// XCD-swizzled 1D grid (1536): each XCD owns an m-band (8 A-panels resident in its L2).
__global__ __launch_bounds__(256) void gemm_qkv_kernel(const u16* __restrict__ Aall,
                                                       const u16* __restrict__ Bt3,
                                                       const float* __restrict__ bq,
                                                       const float* __restrict__ bk,
                                                       const float* __restrict__ bv,
                                                       u16* __restrict__ Qm,
                                                       u16* __restrict__ Km,
                                                       u16* __restrict__ Vtm,
                                                       float qscale) {
  __shared__ __align__(16) u16 sA[128 * 64];
  __shared__ __align__(16) u16 sB[128 * 64];
  const int tid  = threadIdx.x;
  const int lane = tid & 63;
  const int w    = tid >> 6;
  const int wm   = (w >> 1) * 64;
  const int wn   = (w & 1) * 64;
  const int lrow = lane & 15;
  const int lc16 = lane >> 4;             // 16B-column index within 32-elem K chunk
  // XCD swizzle: XCD k = o&7 gets m-panels [8k,8k+8), n fast within
  const int o  = blockIdx.x;
  const int k  = o & 7, j = o >> 3;       // j 0..191
  const int n0 = (j >> 3) * 128;          // 0..2944
  const int m0 = (k * 8 + (j & 7)) * 128; // 0..8064
  const int sel = n0 >> 10;

  const u16* Ab = Aall + (size_t)sel * 8192 * 1024 + (size_t)m0 * GK;
  const u16* Bb = Bt3 + (size_t)n0 * GK;
  const float* bias = sel == 0 ? bq : (sel == 1 ? bk : bv);
  const float osc = sel == 0 ? qscale : 1.f;
  u16* outp = sel == 0 ? Qm : (sel == 1 ? Km : Vtm);

  f32x4 acc[4][4] = {};

  for (int kt = 0; kt < GK; kt += 64) {
    __syncthreads();
#pragma unroll
    for (int i = 0; i < 4; ++i) {
      const int seg = tid + i * 256;
      const int row = seg >> 3, c = seg & 7;
      const int csw = (c ^ (row & 7)) * 8;     // pre-swizzled source column
      gload_lds16(Ab + (size_t)row * GK + kt + csw, &sA[seg * 8]);
      gload_lds16(Bb + (size_t)row * GK + kt + csw, &sB[seg * 8]);
    }
    __syncthreads();   // drains vmcnt
#pragma unroll
    for (int kk = 0; kk < 64; kk += 32) {
      const int c16 = (kk >> 3) + lc16;
      u16x8 am[4], bn[4];
#pragma unroll
      for (int m = 0; m < 4; ++m)
        am[m] = rd_swz(sA, wm + m * 16 + lrow, c16);
#pragma unroll
      for (int n = 0; n < 4; ++n)
        bn[n] = rd_swz(sB, wn + n * 16 + lrow, c16);
#pragma unroll
      for (int m = 0; m < 4; ++m)
#pragma unroll
        for (int n = 0; n < 4; ++n)
          acc[m][n] = mfma16(am[m], bn[n], acc[m][n]);
    }
  }

  const int r0 = (lane >> 4) * 4;
#pragma unroll
  for (int m = 0; m < 4; ++m) {
#pragma unroll
    for (int n = 0; n < 4; ++n) {
      const int col = n0 + wn + n * 16 + lrow;
      const int c = col & 1023;
      const float bval = bias[c];
      const int h = c >> 6, d = c & 63;
#pragma unroll
      for (int r = 0; r < 4; ++r) {
        const int row = m0 + wm + m * 16 + r0 + r;
        const float v = (acc[m][n][r] + bval) * osc;
        const int bb = row >> 11, s = row & (SEQ - 1);
        size_t off;
        if (sel == 2) off = (((size_t)(bb * NH + h)) * 64 + d) * SEQ + s;
        else          off = (((size_t)(bb * NH + h)) * SEQ + s) * 64 + d;
        outp[off] = f2bf(v);
      }
    }
  }
}

// ---------------------------------------------------------------- output GEMM (fp32 out)
__global__ __launch_bounds__(256) void gemm_o_kernel(const u16* __restrict__ A,
                                                     const u16* __restrict__ Bt,
                                                     const float* __restrict__ bias,
                                                     float* __restrict__ out) {
  __shared__ __align__(16) u16 sA[128 * 64];
  __shared__ __align__(16) u16 sB[128 * 64];
  const int tid  = threadIdx.x;
  const int lane = tid & 63;
  const int w    = tid >> 6;
  const int wm   = (w >> 1) * 64;
  const int wn   = (w & 1) * 64;
  const int lrow = lane & 15;
  const int lc16 = lane >> 4;
  const int o  = blockIdx.x;              // 512 blocks
  const int k  = o & 7, j = o >> 3;       // j 0..63
  const int n0 = (j >> 3) * 128;
  const int m0 = (k * 8 + (j & 7)) * 128;

  const u16* Ab = A + (size_t)m0 * GK;
  const u16* Bb = Bt + (size_t)n0 * GK;

  f32x4 acc[4][4] = {};

  for (int kt = 0; kt < GK; kt += 64) {
    __syncthreads();
#pragma unroll
    for (int i = 0; i < 4; ++i) {
      const int seg = tid + i * 256;
      const int row = seg >> 3, c = seg & 7;
      const int csw = (c ^ (row & 7)) * 8;
      gload_lds16(Ab + (size_t)row * GK + kt + csw, &sA[seg * 8]);
      gload_lds16(Bb + (size_t)row * GK + kt + csw, &sB[seg * 8]);
    }
    __syncthreads();
#pragma unroll
    for (int kk = 0; kk < 64; kk += 32) {
      const int c16 = (kk >> 3) + lc16;
      u16x8 am[4], bn[4];
#pragma unroll
      for (int m = 0; m < 4; ++m)
        am[m] = rd_swz(sA, wm + m * 16 + lrow, c16);
#pragma unroll
      for (int n = 0; n < 4; ++n)
        bn[n] = rd_swz(sB, wn + n * 16 + lrow, c16);
#pragma unroll
      for (int m = 0; m < 4; ++m)
#pragma unroll
        for (int n = 0; n < 4; ++n)
          acc[m][n] = mfma16(am[m], bn[n], acc[m][n]);
    }
  }

  const int r0 = (lane >> 4) * 4;
#pragma unroll
  for (int m = 0; m < 4; ++m) {
#pragma unroll
    for (int n = 0; n < 4; ++n) {
      const int col = n0 + wn + n * 16 + lrow;
      const float bval = bias[col];
#pragma unroll
      for (int r = 0; r < 4; ++r) {
        const int row = m0 + wm + m * 16 + r0 + r;
        out[(size_t)row * DM + col] = acc[m][n][r] + bval;
      }
    }
  }
}

// ---------------------------------------------------------------- flash attention (swapped-QK 32x32)
// Q (pre-scaled by 0.125*log2e), K: bf16 [B,H,S,64]; Vt: bf16 [B,H,64,S]; att: bf16 [B,S,H*64]
// R6-proven body. LPT pairing: block does qb=p AND qb=15-p (uniform 34 tiles/block).
// XCD-swizzled grid (512): each XCD owns 8 bh (4 MB K/V = one L2).
__global__ __launch_bounds__(256) void attn_kernel(const u16* __restrict__ Qm,
                                                   const u16* __restrict__ Km,
                                                   const u16* __restrict__ Vtm,
                                                   const int* __restrict__ vlen,
                                                   u16* __restrict__ att) {
  __shared__ __align__(16) u16 smem[8192];            // 16 KB
  char* lds_k = (char*)smem;                          // K tile  [64 k][64 dh], swizzled
  char* lds_v = (char*)smem + 8192;                   // Vt tile [64 d][64 k],  swizzled
  const int tid  = threadIdx.x;
  const int lane = tid & 63;
  const int w    = tid >> 6;
  const int ql   = lane & 31;
  const int hi   = lane >> 5;
  const int hi4  = hi * 4;
  // XCD swizzle + pairing: o -> (bh, pidx)
  const int o   = blockIdx.x;                 // 0..511
  const int t   = (o & 7) * 64 + (o >> 3);    // bijective
  const int bh  = t >> 3;
  const int pidx = t & 7;
  const int b    = bh >> 4;
  const int h    = bh & 15;
  const int valid = vlen[b];
  const float NEGB = -1e30f;

  const u16* Kg = Km + (size_t)bh * SEQ * 64;
  const u16* Vg = Vtm + (size_t)bh * 64 * SEQ;

  for (int pass = 0; pass < 2; ++pass) {
    const int qb  = pass == 0 ? pidx : 15 - pidx;
    const int q0  = qb * 128;
    const int q0w = q0 + w * 32;
    const int qg  = q0w + ql;

    const u16* Qbase = Qm + ((size_t)bh * SEQ + qg) * 64 + hi * 8;
    u16x8 qf[4];
#pragma unroll
    for (int s = 0; s < 4; ++s) qf[s] = *(const u16x8*)(Qbase + s * 16);

    f32x16 acc_o[2] = {};
    float m_run = NEGB, l_run = 0.f;

    const int kb_max = min((q0 + 127) >> 6, (valid - 1) >> 6);
    const int rel_base = min(qg, valid - 1);

    for (int kb = 0; kb <= kb_max; ++kb) {
      __syncthreads();
      // stage K and V^T tiles (reg -> swizzled ds_write: byte ^= (row&7)<<4)
#pragma unroll
      for (int i = 0; i < 2; ++i) {
        const int seg = tid + i * 256;   // 512 segs of 16B per tile
        const int row = seg >> 3, c = seg & 7;
        const int dst = (row * 128 + c * 16) ^ ((row & 7) << 4);
        *(u16x8*)(lds_k + dst) = *(const u16x8*)(Kg + ((size_t)(kb * 64 + row)) * 64 + c * 8);
        *(u16x8*)(lds_v + dst) = *(const u16x8*)(Vg + (size_t)row * SEQ + kb * 64 + c * 8);
      }
      __syncthreads();

      if (kb * 64 > q0w + 31) continue;  // tile fully masked for this wave

      // ---- QK^T: S^T[k][q] (log2 domain; Q pre-scaled)
      f32x16 s_acc[2] = {};
      __builtin_amdgcn_s_setprio(1);
#pragma unroll
      for (int ch = 0; ch < 2; ++ch) {
#pragma unroll
        for (int s = 0; s < 4; ++s) {
          const int krow = ch * 32 + ql;
          const int off = (krow * 128 + s * 32 + hi * 16) ^ ((krow & 7) << 4);
          u16x8 kf = *(const u16x8*)(lds_k + off);
          s_acc[ch] = mfma32(kf, qf[s], s_acc[ch]);
        }
      }
      __builtin_amdgcn_s_setprio(0);

      // ---- mask + online softmax (lane-local per q)
      const int rel = rel_base - kb * 64;
      float mrow = NEGB;
#pragma unroll
      for (int ch = 0; ch < 2; ++ch)
#pragma unroll
        for (int r = 0; r < 16; ++r) {
          const int koff = ch * 32 + (r & 3) + 8 * (r >> 2) + hi4;
          float tv = s_acc[ch][r];
          tv = (koff > rel) ? NEGB : tv;
          s_acc[ch][r] = tv;
          mrow = fmaxf(mrow, tv);
        }
      mrow = fmaxf(mrow, __shfl_xor(mrow, 32));
      const float mnew = fmaxf(m_run, mrow);
      const float sc_o = fast_exp2(m_run - mnew);
      m_run = mnew;
      float rs = 0.f;
#pragma unroll
      for (int ch = 0; ch < 2; ++ch)
#pragma unroll
        for (int r = 0; r < 16; ++r) {
          const float p = fast_exp2(s_acc[ch][r] - mnew);
          s_acc[ch][r] = p;
          rs += p;
        }
      rs += __shfl_xor(rs, 32);
      l_run = l_run * sc_o + rs;
#pragma unroll
      for (int dc = 0; dc < 2; ++dc)
#pragma unroll
        for (int r = 0; r < 16; ++r) acc_o[dc][r] *= sc_o;

      // ---- P^T -> B-operand frags via cvt_pk + permlane32_swap
      u16x8 pa[4];
#pragma unroll
      for (int ch = 0; ch < 2; ++ch) {
#pragma unroll
        for (int half = 0; half < 2; ++half) {
          const int pb = half * 8;
          u32 x0 = cvt_pk_bf16(s_acc[ch][pb + 0], s_acc[ch][pb + 1]);
          u32 x1 = cvt_pk_bf16(s_acc[ch][pb + 2], s_acc[ch][pb + 3]);
          u32 y0 = cvt_pk_bf16(s_acc[ch][pb + 4], s_acc[ch][pb + 5]);
          u32 y1 = cvt_pk_bf16(s_acc[ch][pb + 6], s_acc[ch][pb + 7]);
          u32x2 r0 = __builtin_amdgcn_permlane32_swap(x0, y0, false, false);
          u32x2 r1 = __builtin_amdgcn_permlane32_swap(x1, y1, false, false);
          u32x4 wds = {r0[0], r1[0], r0[1], r1[1]};
          pa[ch * 2 + half] = __builtin_bit_cast(u16x8, wds);
        }
      }

      // ---- PV: O^T[d][q] += V^T[d][k] * P^T[k][q]
      __builtin_amdgcn_s_setprio(1);
#pragma unroll
      for (int dc = 0; dc < 2; ++dc) {
#pragma unroll
        for (int ks = 0; ks < 4; ++ks) {
          const int drow = dc * 32 + ql;
          const int off = (drow * 128 + ks * 32 + hi * 16) ^ ((drow & 7) << 4);
          u16x8 vf = *(const u16x8*)(lds_v + off);
          acc_o[dc] = mfma32(vf, pa[ks], acc_o[dc]);
        }
      }
      __builtin_amdgcn_s_setprio(0);
    }

    // ---- epilogue: normalize, transpose via LDS, coalesced store
    __syncthreads();
    const float inv_l = 1.f / l_run;
    char* wbase = (char*)smem + w * 4096;   // per-wave 32q x 64d bf16 region
#pragma unroll
    for (int dc = 0; dc < 2; ++dc)
#pragma unroll
      for (int rg = 0; rg < 4; ++rg) {
        u32 lo  = cvt_pk_bf16(acc_o[dc][rg * 4 + 0] * inv_l, acc_o[dc][rg * 4 + 1] * inv_l);
        u32 hiw = cvt_pk_bf16(acc_o[dc][rg * 4 + 2] * inv_l, acc_o[dc][rg * 4 + 3] * inv_l);
        const int dbase = dc * 32 + rg * 8 + hi4;
        const int off = (ql * 128 + dbase * 2) ^ ((ql & 7) << 4);
        u32x2 pr = {lo, hiw};
        *(u32x2*)(wbase + off) = pr;
      }
    __syncthreads();
    u16* attb = att + ((size_t)b * SEQ + q0) * DM + h * 64;
#pragma unroll
    for (int i = 0; i < 4; ++i) {
      const int seg = tid + i * 256;       // 1024 segs of 16B
      const int qr = seg >> 3, c = seg & 7;
      const int off = ((qr & 31) * 128 + c * 16) ^ ((qr & 7) << 4);
      u16x8 vvv = *(const u16x8*)((char*)smem + (qr >> 5) * 4096 + off);
      *(u16x8*)(attb + (size_t)qr * DM + c * 8) = vvv;
    }
  }
}

// ---------------------------------------------------------------- launch
extern "C" void kernel_launch(void* const* d_in, const int* in_sizes, int n_in,
                              void* d_out, int out_size, void* d_ws, size_t ws_size,
                              hipStream_t stream) {
  const float* q_in = (const float*)d_in[0];
  const float* k_in = (const float*)d_in[1];
  const float* v_in = (const float*)d_in[2];
  const int*   kpm  = (const int*)d_in[3];
  const float* Wq   = (const float*)d_in[4];
  const float* bq   = (const float*)d_in[5];
  const float* Wk   = (const float*)d_in[6];
  const float* bk   = (const float*)d_in[7];
  const float* Wv   = (const float*)d_in[8];
  const float* bv   = (const float*)d_in[9];
  const float* Wo   = (const float*)d_in[10];
  const float* bo   = (const float*)d_in[11];

  char* ws = (char*)d_ws;
  const size_t WSZ = (size_t)1 << 21;   // 2 MB per transposed weight
  const size_t TSZ = (size_t)1 << 24;   // 16 MB per bf16 [8192,1024] tensor
  u16* wqkv_t = (u16*)(ws);                          // [3072][1024] (+ Wo at 3*WSZ)
  u16* wo_t   = (u16*)(ws + 3 * WSZ);
  u16* qkvA   = (u16*)(ws + 4 * WSZ);                // 3 contiguous bf16 activations
  u16* Qm     = (u16*)(ws + 4 * WSZ + 3 * TSZ);
  u16* Km     = (u16*)(ws + 4 * WSZ + 4 * TSZ);
  u16* Vtm    = (u16*)(ws + 4 * WSZ + 5 * TSZ);
  u16* attb   = qkvA;                                // alias: qkvA dead after QKV-GEMM
  int* vlen   = (int*)(ws + 4 * WSZ + 6 * TSZ);

  const float SC = 0.18033688011112042f;  // 0.125 * log2(e), folded into Q

  vlen_kernel<<<NB, 256, 0, stream>>>(kpm, vlen);
  transpose4_kernel<<<dim3(32, 32, 4), dim3(32, 8), 0, stream>>>(Wq, Wk, Wv, Wo, wqkv_t);
  cast3_kernel<<<dim3(4096, 3), 256, 0, stream>>>(q_in, k_in, v_in, qkvA);

  gemm_qkv_kernel<<<1536, 256, 0, stream>>>(qkvA, wqkv_t, bq, bk, bv, Qm, Km, Vtm, SC);

  attn_kernel<<<512, 256, 0, stream>>>(Qm, Km, Vtm, vlen, attb);

  gemm_o_kernel<<<512, 256, 0, stream>>>(attb, wo_t, bo, (float*)d_out);
}

// Round 12
// 334.461 us; speedup vs baseline: 1.5263x; 1.0065x over previous
//
#include <hip/hip_runtime.h>

typedef unsigned short u16;
typedef unsigned int u32;
typedef u16 u16x8 __attribute__((ext_vector_type(8)));
typedef u32 u32x2 __attribute__((ext_vector_type(2)));
typedef u32 u32x4 __attribute__((ext_vector_type(4)));
typedef __bf16 bf16x8 __attribute__((ext_vector_type(8)));
typedef float f32x4 __attribute__((ext_vector_type(4)));
typedef float f32x16 __attribute__((ext_vector_type(16)));

typedef __attribute__((address_space(1))) const u32 gas_u32;
typedef __attribute__((address_space(3))) u32 las_u32;

__device__ __forceinline__ u16 f2bf(float f) {
  unsigned u = __builtin_bit_cast(unsigned, f);
  u += 0x7FFF + ((u >> 16) & 1);   // RNE
  return (u16)(u >> 16);
}

__device__ __forceinline__ float fast_exp2(float x) {
  return __builtin_amdgcn_exp2f(x);
}

__device__ __forceinline__ f32x4 mfma16(u16x8 a, u16x8 b, f32x4 c) {
  return __builtin_amdgcn_mfma_f32_16x16x32_bf16(
      __builtin_bit_cast(bf16x8, a), __builtin_bit_cast(bf16x8, b), c, 0, 0, 0);
}

__device__ __forceinline__ f32x16 mfma32(u16x8 a, u16x8 b, f32x16 c) {
  return __builtin_amdgcn_mfma_f32_32x32x16_bf16(
      __builtin_bit_cast(bf16x8, a), __builtin_bit_cast(bf16x8, b), c, 0, 0, 0);
}

__device__ __forceinline__ u32 cvt_pk_bf16(float lo, float hi) {
  u32 r;
  asm("v_cvt_pk_bf16_f32 %0, %1, %2" : "=v"(r) : "v"(lo), "v"(hi));
  return r;
}

// async global->LDS, 16B per lane (linear LDS dest = wave-uniform base + lane*16)
__device__ __forceinline__ void gload_lds16(const u16* g, u16* l) {
  __builtin_amdgcn_global_load_lds((gas_u32*)(const void*)g, (las_u32*)(void*)l, 16, 0, 0);
}

// ---------------------------------------------------------------- constants
constexpr int DM   = 1024;   // d_model
constexpr int GK   = 1024;   // GEMM K
constexpr int SEQ  = 2048;
constexpr int NB   = 4;
constexpr int NH   = 16;

// ---------------------------------------------------------------- fused fp32 -> bf16 cast (q,k,v)
__global__ __launch_bounds__(256) void cast3_kernel(const float* __restrict__ q,
                                                    const float* __restrict__ k,
                                                    const float* __restrict__ v,
                                                    u16* __restrict__ out) {
  const int t = blockIdx.y;
  const float* in = t == 0 ? q : (t == 1 ? k : v);
  u16* dst = out + (size_t)t * 8192 * 1024;
  const int i = blockIdx.x * 256 + threadIdx.x;
  float4 a = ((const float4*)in)[2 * i];
  float4 b = ((const float4*)in)[2 * i + 1];
  u16x8 o = {f2bf(a.x), f2bf(a.y), f2bf(a.z), f2bf(a.w),
             f2bf(b.x), f2bf(b.y), f2bf(b.z), f2bf(b.w)};
  *(u16x8*)(dst + (size_t)i * 8) = o;
}

// ---------------------------------------------------------------- fused weight transpose+cast (4 W)
__global__ void transpose4_kernel(const float* __restrict__ Wq, const float* __restrict__ Wk,
                                  const float* __restrict__ Wv, const float* __restrict__ Wo,
                                  u16* __restrict__ Wt) {
  __shared__ float tile[32][33];
  const int z = blockIdx.z;
  const float* W = z == 0 ? Wq : (z == 1 ? Wk : (z == 2 ? Wv : Wo));
  u16* dst = Wt + (size_t)z * DM * DM;
  const int tx = threadIdx.x;          // 0..31
  const int ty = threadIdx.y;          // 0..7
  const int n0 = blockIdx.x * 32;
  const int k0 = blockIdx.y * 32;
#pragma unroll
  for (int i = 0; i < 4; ++i)
    tile[ty + i * 8][tx] = W[(size_t)(k0 + ty + i * 8) * DM + n0 + tx];
  __syncthreads();
#pragma unroll
  for (int i = 0; i < 4; ++i)
    dst[(size_t)(n0 + ty + i * 8) * DM + k0 + tx] = f2bf(tile[tx][ty + i * 8]);
}

// ---------------------------------------------------------------- valid_len from key padding mask
__global__ void vlen_kernel(const int* __restrict__ mask, int* __restrict__ vlen) {
  const int b = blockIdx.x;
  const int t = threadIdx.x;
  __shared__ int cnt[256];
  int c = 0;
  for (int s = t; s < SEQ; s += 256) c += (mask[b * SEQ + s] == 0) ? 1 : 0;
  cnt[t] = c;
  __syncthreads();
  for (int off = 128; off > 0; off >>= 1) {
    if (t < off) cnt[t] += cnt[t + off];
    __syncthreads();
  }
  if (t == 0) vlen[b] = cnt[0];
}

// LDS tile addressing (T2 swizzle, rule #21 both-sides):
//   staging: LDS dest linear (slot = seg*16B); global source col = (c ^ (row&7))
//   read:    byte off = row*128 + ((c16 ^ (row&7)) << 4)
__device__ __forceinline__ u16x8 rd_swz(const u16* s, int row, int c16) {
  return *(const u16x8*)((const char*)s + row * 128 + (((c16 ^ (row & 7)) & 7) << 4));
}

// ---------------------------------------------------------------- fused QKV GEMM (one dispatch)
// XCD-swizzled 1D grid (1536). T3-minimum schedule: double-buffered LDS, prefetch
// next K-tile issued BEFORE current compute, one vmcnt(0)+barrier per iter.
__global__ __launch_bounds__(256) void gemm_qkv_kernel(const u16* __restrict__ Aall,
                                                       const u16* __restrict__ Bt3,
                                                       const float* __restrict__ bq,
                                                       const float* __restrict__ bk,
                                                       const float* __restrict__ bv,
                                                       u16* __restrict__ Qm,
                                                       u16* __restrict__ Km,
                                                       u16* __restrict__ Vtm,
                                                       float qscale) {
  __shared__ __align__(16) u16 sA[2][128 * 64];
  __shared__ __align__(16) u16 sB[2][128 * 64];
  const int tid  = threadIdx.x;
  const int lane = tid & 63;
  const int w    = tid >> 6;
  const int wm   = (w >> 1) * 64;
  const int wn   = (w & 1) * 64;
  const int lrow = lane & 15;
  const int lc16 = lane >> 4;             // 16B-column index within 32-elem K chunk
  // XCD swizzle: XCD k = o&7 gets m-panels [8k,8k+8), n fast within
  const int o  = blockIdx.x;
  const int k  = o & 7, j = o >> 3;       // j 0..191
  const int n0 = (j >> 3) * 128;          // 0..2944
  const int m0 = (k * 8 + (j & 7)) * 128; // 0..8064
  const int sel = n0 >> 10;

  const u16* Ab = Aall + (size_t)sel * 8192 * 1024 + (size_t)m0 * GK;
  const u16* Bb = Bt3 + (size_t)n0 * GK;
  const float* bias = sel == 0 ? bq : (sel == 1 ? bk : bv);
  const float osc = sel == 0 ? qscale : 1.f;
  u16* outp = sel == 0 ? Qm : (sel == 1 ? Km : Vtm);

  f32x4 acc[4][4] = {};

  auto STAGE = [&](int bf, int kt) {
#pragma unroll
    for (int i = 0; i < 4; ++i) {
      const int seg = tid + i * 256;
      const int row = seg >> 3, c = seg & 7;
      const int csw = (c ^ (row & 7)) * 8;     // pre-swizzled source column
      gload_lds16(Ab + (size_t)row * GK + kt + csw, &sA[bf][seg * 8]);
      gload_lds16(Bb + (size_t)row * GK + kt + csw, &sB[bf][seg * 8]);
    }
  };

  STAGE(0, 0);
  asm volatile("s_waitcnt vmcnt(0)" ::: "memory");
  __syncthreads();
  int bf = 0;

  for (int kt = 0; kt < GK; kt += 64) {
    if (kt + 64 < GK) STAGE(bf ^ 1, kt + 64);   // prefetch next tile (other buffer)
#pragma unroll
    for (int kk = 0; kk < 64; kk += 32) {
      const int c16 = (kk >> 3) + lc16;
      u16x8 am[4], bn[4];
#pragma unroll
      for (int m = 0; m < 4; ++m)
        am[m] = rd_swz(sA[bf], wm + m * 16 + lrow, c16);
#pragma unroll
      for (int n = 0; n < 4; ++n)
        bn[n] = rd_swz(sB[bf], wn + n * 16 + lrow, c16);
#pragma unroll
      for (int m = 0; m < 4; ++m)
#pragma unroll
        for (int n = 0; n < 4; ++n)
          acc[m][n] = mfma16(am[m], bn[n], acc[m][n]);
    }
    asm volatile("s_waitcnt vmcnt(0)" ::: "memory");  // prefetch landed
    __syncthreads();                                  // all reads of bf done
    bf ^= 1;
  }

  const int r0 = (lane >> 4) * 4;
#pragma unroll
  for (int m = 0; m < 4; ++m) {
#pragma unroll
    for (int n = 0; n < 4; ++n) {
      const int col = n0 + wn + n * 16 + lrow;
      const int c = col & 1023;
      const float bval = bias[c];
      const int h = c >> 6, d = c & 63;
#pragma unroll
      for (int r = 0; r < 4; ++r) {
        const int row = m0 + wm + m * 16 + r0 + r;
        const float v = (acc[m][n][r] + bval) * osc;
        const int bb = row >> 11, s = row & (SEQ - 1);
        size_t off;
        if (sel == 2) off = (((size_t)(bb * NH + h)) * 64 + d) * SEQ + s;
        else          off = (((size_t)(bb * NH + h)) * SEQ + s) * 64 + d;
        outp[off] = f2bf(v);
      }
    }
  }
}

// ---------------------------------------------------------------- output GEMM (fp32 out)
// UNCHANGED single-buffer structure — within-run control for the dbuf A/B.
__global__ __launch_bounds__(256) void gemm_o_kernel(const u16* __restrict__ A,
                                                     const u16* __restrict__ Bt,
                                                     const float* __restrict__ bias,
                                                     float* __restrict__ out) {
  __shared__ __align__(16) u16 sA[128 * 64];
  __shared__ __align__(16) u16 sB[128 * 64];
  const int tid  = threadIdx.x;
  const int lane = tid & 63;
  const int w    = tid >> 6;
  const int wm   = (w >> 1) * 64;
  const int wn   = (w & 1) * 64;
  const int lrow = lane & 15;
  const int lc16 = lane >> 4;
  const int o  = blockIdx.x;              // 512 blocks
  const int k  = o & 7, j = o >> 3;       // j 0..63
  const int n0 = (j >> 3) * 128;
  const int m0 = (k * 8 + (j & 7)) * 128;

  const u16* Ab = A + (size_t)m0 * GK;
  const u16* Bb = Bt + (size_t)n0 * GK;

  f32x4 acc[4][4] = {};

  for (int kt = 0; kt < GK; kt += 64) {
    __syncthreads();
#pragma unroll
    for (int i = 0; i < 4; ++i) {
      const int seg = tid + i * 256;
      const int row = seg >> 3, c = seg & 7;
      const int csw = (c ^ (row & 7)) * 8;
      gload_lds16(Ab + (size_t)row * GK + kt + csw, &sA[seg * 8]);
      gload_lds16(Bb + (size_t)row * GK + kt + csw, &sB[seg * 8]);
    }
    __syncthreads();
#pragma unroll
    for (int kk = 0; kk < 64; kk += 32) {
      const int c16 = (kk >> 3) + lc16;
      u16x8 am[4], bn[4];
#pragma unroll
      for (int m = 0; m < 4; ++m)
        am[m] = rd_swz(sA, wm + m * 16 + lrow, c16);
#pragma unroll
      for (int n = 0; n < 4; ++n)
        bn[n] = rd_swz(sB, wn + n * 16 + lrow, c16);
#pragma unroll
      for (int m = 0; m < 4; ++m)
#pragma unroll
        for (int n = 0; n < 4; ++n)
          acc[m][n] = mfma16(am[m], bn[n], acc[m][n]);
    }
  }

  const int r0 = (lane >> 4) * 4;
#pragma unroll
  for (int m = 0; m < 4; ++m) {
#pragma unroll
    for (int n = 0; n < 4; ++n) {
      const int col = n0 + wn + n * 16 + lrow;
      const float bval = bias[col];
#pragma unroll
      for (int r = 0; r < 4; ++r) {
        const int row = m0 + wm + m * 16 + r0 + r;
        out[(size_t)row * DM + col] = acc[m][n][r] + bval;
      }
    }
  }
}

// ---------------------------------------------------------------- flash attention (swapped-QK 32x32)
// Q (pre-scaled by 0.125*log2e), K: bf16 [B,H,S,64]; Vt: bf16 [B,H,64,S]; att: bf16 [B,S,H*64]
// R6-proven body. LPT pairing: block does qb=p AND qb=15-p (uniform 34 tiles/block).
// XCD-swizzled grid (512): each XCD owns 8 bh (4 MB K/V = one L2).
__global__ __launch_bounds__(256) void attn_kernel(const u16* __restrict__ Qm,
                                                   const u16* __restrict__ Km,
                                                   const u16* __restrict__ Vtm,
                                                   const int* __restrict__ vlen,
                                                   u16* __restrict__ att) {
  __shared__ __align__(16) u16 smem[8192];            // 16 KB
  char* lds_k = (char*)smem;                          // K tile  [64 k][64 dh], swizzled
  char* lds_v = (char*)smem + 8192;                   // Vt tile [64 d][64 k],  swizzled
  const int tid  = threadIdx.x;
  const int lane = tid & 63;
  const int w    = tid >> 6;
  const int ql   = lane & 31;
  const int hi   = lane >> 5;
  const int hi4  = hi * 4;
  // XCD swizzle + pairing: o -> (bh, pidx)
  const int o   = blockIdx.x;                 // 0..511
  const int t   = (o & 7) * 64 + (o >> 3);    // bijective
  const int bh  = t >> 3;
  const int pidx = t & 7;
  const int b    = bh >> 4;
  const int h    = bh & 15;
  const int valid = vlen[b];
  const float NEGB = -1e30f;

  const u16* Kg = Km + (size_t)bh * SEQ * 64;
  const u16* Vg = Vtm + (size_t)bh * 64 * SEQ;

  for (int pass = 0; pass < 2; ++pass) {
    const int qb  = pass == 0 ? pidx : 15 - pidx;
    const int q0  = qb * 128;
    const int q0w = q0 + w * 32;
    const int qg  = q0w + ql;

    const u16* Qbase = Qm + ((size_t)bh * SEQ + qg) * 64 + hi * 8;
    u16x8 qf[4];
#pragma unroll
    for (int s = 0; s < 4; ++s) qf[s] = *(const u16x8*)(Qbase + s * 16);

    f32x16 acc_o[2] = {};
    float m_run = NEGB, l_run = 0.f;

    const int kb_max = min((q0 + 127) >> 6, (valid - 1) >> 6);
    const int rel_base = min(qg, valid - 1);

    for (int kb = 0; kb <= kb_max; ++kb) {
      __syncthreads();
      // stage K and V^T tiles (reg -> swizzled ds_write: byte ^= (row&7)<<4)
#pragma unroll
      for (int i = 0; i < 2; ++i) {
        const int seg = tid + i * 256;   // 512 segs of 16B per tile
        const int row = seg >> 3, c = seg & 7;
        const int dst = (row * 128 + c * 16) ^ ((row & 7) << 4);
        *(u16x8*)(lds_k + dst) = *(const u16x8*)(Kg + ((size_t)(kb * 64 + row)) * 64 + c * 8);
        *(u16x8*)(lds_v + dst) = *(const u16x8*)(Vg + (size_t)row * SEQ + kb * 64 + c * 8);
      }
      __syncthreads();

      if (kb * 64 > q0w + 31) continue;  // tile fully masked for this wave

      // ---- QK^T: S^T[k][q] (log2 domain; Q pre-scaled)
      f32x16 s_acc[2] = {};
      __builtin_amdgcn_s_setprio(1);
#pragma unroll
      for (int ch = 0; ch < 2; ++ch) {
#pragma unroll
        for (int s = 0; s < 4; ++s) {
          const int krow = ch * 32 + ql;
          const int off = (krow * 128 + s * 32 + hi * 16) ^ ((krow & 7) << 4);
          u16x8 kf = *(const u16x8*)(lds_k + off);
          s_acc[ch] = mfma32(kf, qf[s], s_acc[ch]);
        }
      }
      __builtin_amdgcn_s_setprio(0);

      // ---- mask + online softmax (lane-local per q)
      const int rel = rel_base - kb * 64;
      float mrow = NEGB;
#pragma unroll
      for (int ch = 0; ch < 2; ++ch)
#pragma unroll
        for (int r = 0; r < 16; ++r) {
          const int koff = ch * 32 + (r & 3) + 8 * (r >> 2) + hi4;
          float tv = s_acc[ch][r];
          tv = (koff > rel) ? NEGB : tv;
          s_acc[ch][r] = tv;
          mrow = fmaxf(mrow, tv);
        }
      mrow = fmaxf(mrow, __shfl_xor(mrow, 32));
      const float mnew = fmaxf(m_run, mrow);
      const float sc_o = fast_exp2(m_run - mnew);
      m_run = mnew;
      float rs = 0.f;
#pragma unroll
      for (int ch = 0; ch < 2; ++ch)
#pragma unroll
        for (int r = 0; r < 16; ++r) {
          const float p = fast_exp2(s_acc[ch][r] - mnew);
          s_acc[ch][r] = p;
          rs += p;
        }
      rs += __shfl_xor(rs, 32);
      l_run = l_run * sc_o + rs;
#pragma unroll
      for (int dc = 0; dc < 2; ++dc)
#pragma unroll
        for (int r = 0; r < 16; ++r) acc_o[dc][r] *= sc_o;

      // ---- P^T -> B-operand frags via cvt_pk + permlane32_swap
      u16x8 pa[4];
#pragma unroll
      for (int ch = 0; ch < 2; ++ch) {
#pragma unroll
        for (int half = 0; half < 2; ++half) {
          const int pb = half * 8;
          u32 x0 = cvt_pk_bf16(s_acc[ch][pb + 0], s_acc[ch][pb + 1]);
          u32 x1 = cvt_pk_bf16(s_acc[ch][pb + 2], s_acc[ch][pb + 3]);
          u32 y0 = cvt_pk_bf16(s_acc[ch][pb + 4], s_acc[ch][pb + 5]);
          u32 y1 = cvt_pk_bf16(s_acc[ch][pb + 6], s_acc[ch][pb + 7]);
          u32x2 r0 = __builtin_amdgcn_permlane32_swap(x0, y0, false, false);
          u32x2 r1 = __builtin_amdgcn_permlane32_swap(x1, y1, false, false);
          u32x4 wds = {r0[0], r1[0], r0[1], r1[1]};
          pa[ch * 2 + half] = __builtin_bit_cast(u16x8, wds);
        }
      }

      // ---- PV: O^T[d][q] += V^T[d][k] * P^T[k][q]
      __builtin_amdgcn_s_setprio(1);
#pragma unroll
      for (int dc = 0; dc < 2; ++dc) {
#pragma unroll
        for (int ks = 0; ks < 4; ++ks) {
          const int drow = dc * 32 + ql;
          const int off = (drow * 128 + ks * 32 + hi * 16) ^ ((drow & 7) << 4);
          u16x8 vf = *(const u16x8*)(lds_v + off);
          acc_o[dc] = mfma32(vf, pa[ks], acc_o[dc]);
        }
      }
      __builtin_amdgcn_s_setprio(0);
    }

    // ---- epilogue: normalize, transpose via LDS, coalesced store
    __syncthreads();
    const float inv_l = 1.f / l_run;
    char* wbase = (char*)smem + w * 4096;   // per-wave 32q x 64d bf16 region
#pragma unroll
    for (int dc = 0; dc < 2; ++dc)
#pragma unroll
      for (int rg = 0; rg < 4; ++rg) {
        u32 lo  = cvt_pk_bf16(acc_o[dc][rg * 4 + 0] * inv_l, acc_o[dc][rg * 4 + 1] * inv_l);
        u32 hiw = cvt_pk_bf16(acc_o[dc][rg * 4 + 2] * inv_l, acc_o[dc][rg * 4 + 3] * inv_l);
        const int dbase = dc * 32 + rg * 8 + hi4;
        const int off = (ql * 128 + dbase * 2) ^ ((ql & 7) << 4);
        u32x2 pr = {lo, hiw};
        *(u32x2*)(wbase + off) = pr;
      }
    __syncthreads();
    u16* attb = att + ((size_t)b * SEQ + q0) * DM + h * 64;
#pragma unroll
    for (int i = 0; i < 4; ++i) {
      const int seg = tid + i * 256;       // 1024 segs of 16B
      const int qr = seg >> 3, c = seg & 7;
      const int off = ((qr & 31) * 128 + c * 16) ^ ((qr & 7) << 4);
      u16x8 vvv = *(const u16x8*)((char*)smem + (qr >> 5) * 4096 + off);
      *(u16x8*)(attb + (size_t)qr * DM + c * 8) = vvv;
    }
  }
}

// ---------------------------------------------------------------- launch
extern "C" void kernel_launch(void* const* d_in, const int* in_sizes, int n_in,
                              void* d_out, int out_size, void* d_ws, size_t ws_size,
                              hipStream_t stream) {
  const float* q_in = (const float*)d_in[0];
  const float* k_in = (const float*)d_in[1];
  const float* v_in = (const float*)d_in[2];
  const int*   kpm  = (const int*)d_in[3];
  const float* Wq   = (const float*)d_in[4];
  const float* bq   = (const float*)d_in[5];
  const float* Wk   = (const float*)d_in[6];
  const float* bk   = (const float*)d_in[7];
  const float* Wv   = (const float*)d_in[8];
  const float* bv   = (const float*)d_in[9];
  const float* Wo   = (const float*)d_in[10];
  const float* bo   = (const float*)d_in[11];

  char* ws = (char*)d_ws;
  const size_t WSZ = (size_t)1 << 21;   // 2 MB per transposed weight
  const size_t TSZ = (size_t)1 << 24;   // 16 MB per bf16 [8192,1024] tensor
  u16* wqkv_t = (u16*)(ws);                          // [3072][1024] (+ Wo at 3*WSZ)
  u16* wo_t   = (u16*)(ws + 3 * WSZ);
  u16* qkvA   = (u16*)(ws + 4 * WSZ);                // 3 contiguous bf16 activations
  u16* Qm     = (u16*)(ws + 4 * WSZ + 3 * TSZ);
  u16* Km     = (u16*)(ws + 4 * WSZ + 4 * TSZ);
  u16* Vtm    = (u16*)(ws + 4 * WSZ + 5 * TSZ);
  u16* attb   = qkvA;                                // alias: qkvA dead after QKV-GEMM
  int* vlen   = (int*)(ws + 4 * WSZ + 6 * TSZ);

  const float SC = 0.18033688011112042f;  // 0.125 * log2(e), folded into Q

  vlen_kernel<<<NB, 256, 0, stream>>>(kpm, vlen);
  transpose4_kernel<<<dim3(32, 32, 4), dim3(32, 8), 0, stream>>>(Wq, Wk, Wv, Wo, wqkv_t);
  cast3_kernel<<<dim3(4096, 3), 256, 0, stream>>>(q_in, k_in, v_in, qkvA);

  gemm_qkv_kernel<<<1536, 256, 0, stream>>>(qkvA, wqkv_t, bq, bk, bv, Qm, Km, Vtm, SC);

  attn_kernel<<<512, 256, 0, stream>>>(Qm, Km, Vtm, vlen, attb);

  gemm_o_kernel<<<512, 256, 0, stream>>>(attb, wo_t, bo, (float*)d_out);
}